// Round 2
// baseline (11315.705 us; speedup 1.0000x reference)
//
#include <hip/hip_runtime.h>
#include <hip/hip_bf16.h>

#define NLAYER 12
#define DMODEL 768
#define NHEAD  12
#define HDIM   64
#define FDIM   3072
#define VOCAB  30522
#define SLEN   512
#define NBATCH 4
#define NTOK   (NBATCH*SLEN)
#define EPSLN  1e-5f

using bf16 = __hip_bfloat16;
typedef __bf16 bf16x8 __attribute__((ext_vector_type(8)));
typedef float  f32x4  __attribute__((ext_vector_type(4)));

__device__ __forceinline__ short f2bs(float f) {
    bf16 h = __float2bfloat16(f);
    return *reinterpret_cast<short*>(&h);
}

// ---------------- reductions ----------------
__device__ __forceinline__ float wave_sum64(float v) {
#pragma unroll
    for (int off = 32; off > 0; off >>= 1) v += __shfl_down(v, off, 64);
    return v;
}
__device__ __forceinline__ float wave_max64(float v) {
#pragma unroll
    for (int off = 32; off > 0; off >>= 1) v = fmaxf(v, __shfl_down(v, off, 64));
    return v;
}
__device__ __forceinline__ float block_sum256(float v, float* red) {
    v = wave_sum64(v);
    __syncthreads();
    if ((threadIdx.x & 63) == 0) red[threadIdx.x >> 6] = v;
    __syncthreads();
    return red[0] + red[1] + red[2] + red[3];
}
__device__ __forceinline__ float block_max256(float v, float* red) {
    v = wave_max64(v);
    __syncthreads();
    if ((threadIdx.x & 63) == 0) red[threadIdx.x >> 6] = v;
    __syncthreads();
    return fmaxf(fmaxf(red[0], red[1]), fmaxf(red[2], red[3]));
}

// ---------------- embedding + LN ----------------
__global__ __launch_bounds__(256) void embed_ln_kernel(
    const int* __restrict__ ids, const float* __restrict__ word,
    const float* __restrict__ pos, const float* __restrict__ seg,
    const float* __restrict__ g, const float* __restrict__ b,
    float* __restrict__ out)
{
    __shared__ float red[4];
    int t = blockIdx.x;
    int s = t & (SLEN - 1);
    long woff = (long)ids[t] * DMODEL;
    float vals[3];
#pragma unroll
    for (int i = 0; i < 3; i++) {
        int d = threadIdx.x + i * 256;
        vals[i] = word[woff + d] + pos[(long)s * DMODEL + d] + seg[d];
    }
    float mu = block_sum256(vals[0] + vals[1] + vals[2], red) * (1.0f / DMODEL);
    float vv = 0.f;
#pragma unroll
    for (int i = 0; i < 3; i++) { float d0 = vals[i] - mu; vv += d0 * d0; }
    float rstd = rsqrtf(block_sum256(vv, red) * (1.0f / DMODEL) + EPSLN);
#pragma unroll
    for (int i = 0; i < 3; i++) {
        int d = threadIdx.x + i * 256;
        out[(long)t * DMODEL + d] = (vals[i] - mu) * rstd * g[d] + b[d];
    }
}

// ---------------- residual + LN ----------------
__global__ __launch_bounds__(256) void ln_res_kernel(
    const float* __restrict__ a, const float* __restrict__ bres,
    const float* __restrict__ g, const float* __restrict__ beta,
    float* __restrict__ out)
{
    __shared__ float red[4];
    long t = blockIdx.x;
    float vals[3];
#pragma unroll
    for (int i = 0; i < 3; i++) {
        int d = threadIdx.x + i * 256;
        vals[i] = a[t * DMODEL + d] + bres[t * DMODEL + d];
    }
    float mu = block_sum256(vals[0] + vals[1] + vals[2], red) * (1.0f / DMODEL);
    float vv = 0.f;
#pragma unroll
    for (int i = 0; i < 3; i++) { float d0 = vals[i] - mu; vv += d0 * d0; }
    float rstd = rsqrtf(block_sum256(vv, red) * (1.0f / DMODEL) + EPSLN);
#pragma unroll
    for (int i = 0; i < 3; i++) {
        int d = threadIdx.x + i * 256;
        out[t * DMODEL + d] = (vals[i] - mu) * rstd * g[d] + beta[d];
    }
}

// ---------------- masked softmax (in-place, f32) ----------------
__global__ __launch_bounds__(256) void softmax_kernel(
    float* __restrict__ attn, const int* __restrict__ amask)
{
    __shared__ float red[4];
    long row = blockIdx.x;                 // b*H*S + h*S + q
    int b = (int)(row / (NHEAD * SLEN));
    float* p = attn + row * SLEN;
    const int* m = amask + (long)b * SLEN;
    int tid = threadIdx.x;
    float v0 = m[tid]       ? p[tid]       : -1e30f;
    float v1 = m[tid + 256] ? p[tid + 256] : -1e30f;
    float mx = block_max256(fmaxf(v0, v1), red);
    float e0 = expf(v0 - mx), e1 = expf(v1 - mx);
    float sum = block_sum256(e0 + e1, red);
    float inv = 1.0f / sum;
    p[tid]       = e0 * inv;
    p[tid + 256] = e1 * inv;
}

// ---------------- V transpose: v[b,s,h,hd] -> vt[b,h,hd,s] ----------------
__global__ __launch_bounds__(256) void transpose_v_kernel(
    const float* __restrict__ v, float* __restrict__ vt)
{
    long i = (long)blockIdx.x * 256 + threadIdx.x;   // over B*H*HD*S
    int s  = (int)(i & (SLEN - 1));
    int hd = (int)((i >> 9) & (HDIM - 1));
    int z  = (int)(i >> 15);                          // b*H + h
    int b = z / NHEAD, hh = z - b * NHEAD;
    vt[i] = v[((long)(b * SLEN + s)) * DMODEL + hh * HDIM + hd];
}

// ---------------- generic 128x128 MFMA GEMM (f32 in/out, bf16 compute) ----
// C[z][M,N] = act( scale * A[z] @ B[z] + bias )
// LAYOUTB==0: B is [K,N] row-major.  LAYOUTB==1: B is [N,K] row-major (B^T).
// per-z offsets: off = (z/zdiv)*s1 + (z%zdiv)*s2
template<int LAYOUTB, int GELU>
__global__ __launch_bounds__(256) void gemm_kernel(
    const float* __restrict__ A, int lda, long sA1, long sA2,
    const float* __restrict__ B, int ldb, long sB1, long sB2,
    float* __restrict__ C, int ldc, long sC1, long sC2,
    int zdiv, const float* __restrict__ bias,
    int M, int N, int K, float scale)
{
    __shared__ short As[128][40];
    __shared__ short Bs[128][40];
    int z = blockIdx.z;
    int zq = z / zdiv, zr = z - zq * zdiv;
    A += zq * sA1 + zr * sA2;
    B += zq * sB1 + zr * sB2;
    C += zq * sC1 + zr * sC2;

    int m0 = blockIdx.y * 128;
    int n0 = blockIdx.x * 128;
    int tid = threadIdx.x;
    int wave = tid >> 6, lane = tid & 63;
    int quad = lane >> 4, l16 = lane & 15;
    int wr = wave >> 1, wc = wave & 1;

    f32x4 acc[4][4];
#pragma unroll
    for (int i = 0; i < 4; i++)
#pragma unroll
        for (int j = 0; j < 4; j++) acc[i][j] = (f32x4){0.f, 0.f, 0.f, 0.f};

    for (int k0 = 0; k0 < K; k0 += 32) {
        __syncthreads();
        // stage A tile [128][32]: 1024 chunks of 4 floats
#pragma unroll
        for (int c = 0; c < 4; c++) {
            int chunk = tid * 4 + c;           // 0..1023
            int row = chunk >> 3;              // 0..127
            int kk  = (chunk & 7) * 4;         // 0..28
            float4 val = *reinterpret_cast<const float4*>(A + (long)(m0 + row) * lda + k0 + kk);
            As[row][kk + 0] = f2bs(val.x);
            As[row][kk + 1] = f2bs(val.y);
            As[row][kk + 2] = f2bs(val.z);
            As[row][kk + 3] = f2bs(val.w);
        }
        if (LAYOUTB == 1) {
#pragma unroll
            for (int c = 0; c < 4; c++) {
                int chunk = tid * 4 + c;
                int row = chunk >> 3;          // n index
                int kk  = (chunk & 7) * 4;
                float4 val = {0.f, 0.f, 0.f, 0.f};
                if (n0 + row < N)
                    val = *reinterpret_cast<const float4*>(B + (long)(n0 + row) * ldb + k0 + kk);
                Bs[row][kk + 0] = f2bs(val.x);
                Bs[row][kk + 1] = f2bs(val.y);
                Bs[row][kk + 2] = f2bs(val.z);
                Bs[row][kk + 3] = f2bs(val.w);
            }
        } else {
#pragma unroll
            for (int c = 0; c < 4; c++) {
                int chunk = tid * 4 + c;       // 32 k-rows x 32 n-chunks
                int krow = chunk >> 5;         // 0..31
                int nn   = (chunk & 31) * 4;   // 0..124
                const float* src = B + (long)(k0 + krow) * ldb + n0 + nn;
#pragma unroll
                for (int e = 0; e < 4; e++) {
                    float f = (n0 + nn + e < N) ? src[e] : 0.f;
                    Bs[nn + e][krow] = f2bs(f);
                }
            }
        }
        __syncthreads();

        bf16x8 afr[4], bfr[4];
#pragma unroll
        for (int i = 0; i < 4; i++)
            afr[i] = *reinterpret_cast<const bf16x8*>(&As[wr * 64 + i * 16 + l16][quad * 8]);
#pragma unroll
        for (int j = 0; j < 4; j++)
            bfr[j] = *reinterpret_cast<const bf16x8*>(&Bs[wc * 64 + j * 16 + l16][quad * 8]);
#pragma unroll
        for (int i = 0; i < 4; i++)
#pragma unroll
            for (int j = 0; j < 4; j++)
                acc[i][j] = __builtin_amdgcn_mfma_f32_16x16x32_bf16(afr[i], bfr[j], acc[i][j], 0, 0, 0);
    }

    // epilogue: C/D layout col=lane&15, row=quad*4+reg
#pragma unroll
    for (int i = 0; i < 4; i++) {
        int rbase = m0 + wr * 64 + i * 16 + quad * 4;
#pragma unroll
        for (int j = 0; j < 4; j++) {
            int col = n0 + wc * 64 + j * 16 + l16;
            if (col < N) {
                float badd = bias ? bias[col] : 0.f;
#pragma unroll
                for (int r = 0; r < 4; r++) {
                    float vv = acc[i][j][r] * scale + badd;
                    if (GELU) vv = 0.5f * vv * (1.0f + erff(vv * 0.70710678118f));
                    C[(long)(rbase + r) * ldc + col] = vv;
                }
            }
        }
    }
}

template<int LAYOUTB, int GELU>
static inline void launch_gemm(hipStream_t stream,
    const float* A, int lda, long sA1, long sA2,
    const float* B, int ldb, long sB1, long sB2,
    float* C, int ldc, long sC1, long sC2,
    int zdiv, const float* bias, int M, int N, int K, float scale, int Z)
{
    dim3 grid((N + 127) / 128, M / 128, Z);
    gemm_kernel<LAYOUTB, GELU><<<grid, 256, 0, stream>>>(
        A, lda, sA1, sA2, B, ldb, sB1, sB2, C, ldc, sC1, sC2,
        zdiv, bias, M, N, K, scale);
}

// ---------------- driver ----------------
extern "C" void kernel_launch(void* const* d_in, const int* in_sizes, int n_in,
                              void* d_out, int out_size, void* d_ws, size_t ws_size,
                              hipStream_t stream)
{
    const int*   ids   = (const int*)d_in[0];
    const int*   amask = (const int*)d_in[1];
    const float* word  = (const float*)d_in[2];
    const float* pos   = (const float*)d_in[3];
    const float* seg   = (const float*)d_in[4];
    const float* eg    = (const float*)d_in[5];
    const float* eb    = (const float*)d_in[6];
    const float* Wq    = (const float*)d_in[7];
    const float* Wk    = (const float*)d_in[8];
    const float* Wv    = (const float*)d_in[9];
    const float* Wo    = (const float*)d_in[10];
    const float* F1w   = (const float*)d_in[11];
    const float* F1b   = (const float*)d_in[12];
    const float* F2w   = (const float*)d_in[13];
    const float* F2b   = (const float*)d_in[14];
    const float* G1    = (const float*)d_in[15];
    const float* B1    = (const float*)d_in[16];
    const float* G2    = (const float*)d_in[17];
    const float* B2    = (const float*)d_in[18];
    const float* OutW  = (const float*)d_in[19];
    const float* OutB  = (const float*)d_in[20];

    float* outp = (float*)d_out;
    float* logits = outp;
    float* attn_base = outp + (long)NTOK * VOCAB;

    float* ws = (float*)d_ws;
    long nd = (long)NTOK * DMODEL;
    float* x  = ws;
    float* q  = ws + nd;
    float* k  = ws + 2 * nd;
    float* v  = ws + 3 * nd;
    float* vt = ws + 4 * nd;
    float* h  = ws + 5 * nd;            // NTOK*FDIM
    // reuse: o -> q, o2 -> k, x1 -> v, h2 -> vt
    float* o  = q;
    float* o2 = k;
    float* x1 = v;
    float* h2 = vt;

    const float scoreScale = 0.036084391824351615f;   // 1/sqrt(768)

    embed_ln_kernel<<<NTOK, 256, 0, stream>>>(ids, word, pos, seg, eg, eb, x);

    for (int l = 0; l < NLAYER; l++) {
        const float* wq  = Wq  + (long)l * DMODEL * DMODEL;
        const float* wk  = Wk  + (long)l * DMODEL * DMODEL;
        const float* wv  = Wv  + (long)l * DMODEL * DMODEL;
        const float* wo  = Wo  + (long)l * DMODEL * DMODEL;
        const float* f1w = F1w + (long)l * DMODEL * FDIM;
        const float* f1b = F1b + (long)l * FDIM;
        const float* f2w = F2w + (long)l * FDIM * DMODEL;
        const float* f2b = F2b + (long)l * DMODEL;
        float* attn_l = attn_base + (long)l * NBATCH * NHEAD * SLEN * SLEN;

        // QKV projections
        launch_gemm<0,0>(stream, x, DMODEL, 0, 0, wq, DMODEL, 0, 0,
                         q, DMODEL, 0, 0, 1, nullptr, NTOK, DMODEL, DMODEL, 1.f, 1);
        launch_gemm<0,0>(stream, x, DMODEL, 0, 0, wk, DMODEL, 0, 0,
                         k, DMODEL, 0, 0, 1, nullptr, NTOK, DMODEL, DMODEL, 1.f, 1);
        launch_gemm<0,0>(stream, x, DMODEL, 0, 0, wv, DMODEL, 0, 0,
                         v, DMODEL, 0, 0, 1, nullptr, NTOK, DMODEL, DMODEL, 1.f, 1);
        transpose_v_kernel<<<(NBATCH*NHEAD*HDIM*SLEN)/256, 256, 0, stream>>>(v, vt);

        // scores = scale * Q K^T  (per b,h) -> attn_l (raw, f32)
        launch_gemm<1,0>(stream,
            q, DMODEL, (long)SLEN * DMODEL, HDIM,
            k, DMODEL, (long)SLEN * DMODEL, HDIM,
            attn_l, SLEN, (long)NHEAD * SLEN * SLEN, (long)SLEN * SLEN,
            NHEAD, nullptr, SLEN, SLEN, HDIM, scoreScale, NBATCH * NHEAD);

        softmax_kernel<<<NBATCH * NHEAD * SLEN, 256, 0, stream>>>(attn_l, amask);

        // o = attn @ V  (per b,h)   (o aliases q)
        launch_gemm<1,0>(stream,
            attn_l, SLEN, (long)NHEAD * SLEN * SLEN, (long)SLEN * SLEN,
            vt, SLEN, (long)NHEAD * HDIM * SLEN, (long)HDIM * SLEN,
            o, DMODEL, (long)SLEN * DMODEL, HDIM,
            NHEAD, nullptr, SLEN, HDIM, SLEN, 1.f, NBATCH * NHEAD);

        // o2 = o @ Wo   (o2 aliases k)
        launch_gemm<0,0>(stream, o, DMODEL, 0, 0, wo, DMODEL, 0, 0,
                         o2, DMODEL, 0, 0, 1, nullptr, NTOK, DMODEL, DMODEL, 1.f, 1);

        ln_res_kernel<<<NTOK, 256, 0, stream>>>(x, o2, G1 + (long)l*DMODEL, B1 + (long)l*DMODEL, x1);

        // h = gelu(x1 @ f1w + f1b)
        launch_gemm<0,1>(stream, x1, DMODEL, 0, 0, f1w, FDIM, 0, 0,
                         h, FDIM, 0, 0, 1, f1b, NTOK, FDIM, DMODEL, 1.f, 1);
        // h2 = h @ f2w + f2b   (h2 aliases vt)
        launch_gemm<0,0>(stream, h, FDIM, 0, 0, f2w, DMODEL, 0, 0,
                         h2, DMODEL, 0, 0, 1, f2b, NTOK, DMODEL, FDIM, 1.f, 1);

        ln_res_kernel<<<NTOK, 256, 0, stream>>>(x1, h2, G2 + (long)l*DMODEL, B2 + (long)l*DMODEL, x);
    }

    // logits = x @ out_w + out_b
    launch_gemm<0,0>(stream, x, DMODEL, 0, 0, OutW, VOCAB, 0, 0,
                     logits, VOCAB, 0, 0, 1, OutB, NTOK, VOCAB, DMODEL, 1.f, 1);
}